// Round 10
// baseline (2575.590 us; speedup 1.0000x reference)
//
#include <hip/hip_runtime.h>
#include <stdint.h>

// Forbid mul+add contraction: pk_fma would change rounding vs the reference's
// separate mul/add ops. Critical scalar math also uses explicit __f*_rn.
#pragma clang fp contract(off)

typedef unsigned long long u64;
typedef unsigned int u32;
typedef float v2f __attribute__((ext_vector_type(2)));

#define BB 8
#define NN 4096
#define SS 1024
#define EE 102      // int(0.1 * 1024)
#define NBB 3072    // N - S
#define FT 256      // fps threads (4 waves, 1 per SIMD)
#define PT 16       // points per thread (contiguous: thread t owns [16t,16t+16))
#define SEL_T 512

// DPP wave64 max-reduce step (bound_ctrl: OOB lanes read 0; values >= 0).
template <int CTRL>
__device__ __forceinline__ float maxdpp(float v) {
  int m = __builtin_amdgcn_update_dpp(0, __float_as_int(v), CTRL, 0xf, 0xf, true);
  return fmaxf(v, __int_as_float(m));
}

// ---------------- FPS kernel: one block per batch ----------------
// Exact replica of _fps_order: d = (dx*dx+dy*dy)+dz*dz (no FMA), mind=min,
// argmax with lowest-index-first ties. r6 proven core (scalar register
// arrays, pk-f32 distances, serial lowest-index select). New vs r6:
//  (a) idxs writes go to LDS hist[] (lgkm ack), flushed after the loop --
//      removes the global write-ack from the per-iter barrier drain path;
//  (b) SoA coord mirror (lxf/lyf/lzf): per-lane candidate prefetch is 3x
//      ds_read_b32 with ~2-way bank aliasing (free), hidden under the DPP
//      chain; winner publishes coords -> no post-reduce dependent LDS read,
//      no second readlane.
__global__ __launch_bounds__(FT) void fps_kernel(const float* __restrict__ x,
                                                 int* __restrict__ idxs) {
  const int b = blockIdx.x;
  const int t = threadIdx.x;
  const int w = t >> 6;
  const int lane = t & 63;
  const float* xb = x + (size_t)b * NN * 3;

  __shared__ float lxf[NN], lyf[NN], lzf[NN]; // 48 KB SoA mirror (+ shield)
  __shared__ int hist[NN];                    // 16 KB FPS order (LDS-local)
  __shared__ u64 rkey[2][4];                  // per-wave key, double-buffered
  __shared__ float rcx[2][4], rcy[2][4], rcz[2][4]; // per-wave coords

  float px[PT], py[PT], pz[PT], mind[PT];

  // load 16 contiguous points = 12 float4 per thread (fully coalesced block)
  const float4* xb4 = (const float4*)xb;
  float4 f[12];
#pragma unroll
  for (int j = 0; j < 12; ++j) f[j] = xb4[t * 12 + j];
#pragma unroll
  for (int g = 0; g < 4; ++g) {
    float4 a = f[g * 3 + 0], c = f[g * 3 + 1], d = f[g * 3 + 2];
    px[g * 4 + 0] = a.x; py[g * 4 + 0] = a.y; pz[g * 4 + 0] = a.z;
    px[g * 4 + 1] = a.w; py[g * 4 + 1] = c.x; pz[g * 4 + 1] = c.y;
    px[g * 4 + 2] = c.z; py[g * 4 + 2] = c.w; pz[g * 4 + 2] = d.x;
    px[g * 4 + 3] = d.y; py[g * 4 + 3] = d.z; pz[g * 4 + 3] = d.w;
  }
#pragma unroll
  for (int q = 0; q < PT; ++q) mind[q] = __builtin_inff();

  // SoA mirror init: 4 float4 stores per array (contiguous 64B per thread)
#pragma unroll
  for (int g = 0; g < 4; ++g) {
    ((float4*)(lxf + t * PT))[g] = make_float4(px[4 * g], px[4 * g + 1],
                                               px[4 * g + 2], px[4 * g + 3]);
    ((float4*)(lyf + t * PT))[g] = make_float4(py[4 * g], py[4 * g + 1],
                                               py[4 * g + 2], py[4 * g + 3]);
    ((float4*)(lzf + t * PT))[g] = make_float4(pz[4 * g], pz[4 * g + 1],
                                               pz[4 * g + 2], pz[4 * g + 3]);
  }
  if (t == 0) {
    hist[0] = 0;
    // initial lp via buf-1 slots: first overwritten at it=1 (after barrier 0)
    rcx[1][0] = px[0]; rcy[1][0] = py[0]; rcz[1][0] = pz[0];
  }
  __syncthreads();
  float lx = rcx[1][0], ly = rcy[1][0], lz = rcz[1][0];

  for (int it = 0; it < NN - 1; ++it) {
    const int buf = it & 1;
    v2f lx2; lx2.x = lx; lx2.y = lx;
    v2f ly2; ly2.x = ly; ly2.y = ly;
    v2f lz2; lz2.x = lz; lz2.y = lz;

    // phase 1: packed-f32 distances + mind update + serial lowest-index
    // select (r6 proven; per-half rn rounding == scalar rn)
    float bestv = -1.0f;
    int bq = 0;
#pragma unroll
    for (int q = 0; q < 8; ++q) {
      v2f X; X.x = px[2 * q]; X.y = px[2 * q + 1];
      v2f Y; Y.x = py[2 * q]; Y.y = py[2 * q + 1];
      v2f Z; Z.x = pz[2 * q]; Z.y = pz[2 * q + 1];
      v2f dx = X - lx2;
      v2f dy = Y - ly2;
      v2f dz = Z - lz2;
      v2f dd = (dx * dx + dy * dy) + dz * dz;
      float m0 = fminf(mind[2 * q], dd.x);
      float m1 = fminf(mind[2 * q + 1], dd.y);
      mind[2 * q] = m0;
      mind[2 * q + 1] = m1;
      // ascending q => ascending global index; strict '>' keeps lowest index
      if (m0 > bestv) { bestv = m0; bq = 2 * q; }
      if (m1 > bestv) { bestv = m1; bq = 2 * q + 1; }
    }

    // phase 1b: prefetch own candidate's coords (SoA b32 x3, ~2-way banks =
    // free; latency hides under the DPP chain + ballot below)
    int ci = t * PT + bq;
    float cx = lxf[ci], cy = lyf[ci], cz = lzf[ci];

    // phase 2: wave64 max via DPP (all VALU), result in lane 63
    float r = bestv;
    r = maxdpp<0x111>(r);   // row_shr:1
    r = maxdpp<0x112>(r);   // row_shr:2
    r = maxdpp<0x114>(r);   // row_shr:4
    r = maxdpp<0x118>(r);   // row_shr:8
    r = maxdpp<0x142>(r);   // row_bcast:15
    r = maxdpp<0x143>(r);   // row_bcast:31
    int wmaxb = __builtin_amdgcn_readlane(__float_as_int(r), 63);

    // phase 3: first lane holding the max == lowest candidate index; that
    // lane publishes its key AND its prefetched coords (no 2nd readlane)
    u64 msk = __ballot(__float_as_int(bestv) == wmaxb);
    int flane = (int)__builtin_ctzll(msk);
    if (lane == flane) {
      int besti = t * PT + bq;
      rkey[buf][w] = ((u64)(u32)wmaxb << 32) | (u32)(0xFFFFFFFFu - (u32)besti);
      rcx[buf][w] = cx; rcy[buf][w] = cy; rcz[buf][w] = cz;
    }
    __syncthreads();

    // phase 4: 4-way key compare (value desc, index asc packed in u64);
    // coords ride along -- no dependent LDS fetch afterwards
    u64 k0 = rkey[buf][0], k1 = rkey[buf][1];
    u64 k2 = rkey[buf][2], k3 = rkey[buf][3];
    float x0 = rcx[buf][0], x1 = rcx[buf][1], x2 = rcx[buf][2], x3 = rcx[buf][3];
    float y0 = rcy[buf][0], y1 = rcy[buf][1], y2 = rcy[buf][2], y3 = rcy[buf][3];
    float z0 = rcz[buf][0], z1 = rcz[buf][1], z2 = rcz[buf][2], z3 = rcz[buf][3];
    bool g01 = k0 > k1;
    u64 ka2 = g01 ? k0 : k1;
    float ax2 = g01 ? x0 : x1, ay2 = g01 ? y0 : y1, az2 = g01 ? z0 : z1;
    bool g23 = k2 > k3;
    u64 kb2 = g23 ? k2 : k3;
    float bx2 = g23 ? x2 : x3, by2 = g23 ? y2 : y3, bz2 = g23 ? z2 : z3;
    bool gf = ka2 > kb2;
    u64 km = gf ? ka2 : kb2;
    lx = gf ? ax2 : bx2; ly = gf ? ay2 : by2; lz = gf ? az2 : bz2;
    int last = (int)(0xFFFFFFFFu - (u32)(km & 0xFFFFFFFFu));
    if (t == 0) hist[it + 1] = last;   // LDS store: lgkm ack only, no vmcnt
  }

  // flush FPS order to global once (coalesced int4)
  __syncthreads();
  int* ig = idxs + (size_t)b * NN;
#pragma unroll
  for (int j = 0; j < NN / FT / 4; ++j) {   // 4096/256/4 = 4 int4 per thread
    ((int4*)ig)[j * FT + t] = ((const int4*)hist)[j * FT + t];
  }
}

// ------------- selection kernel: one block per batch -------------
__global__ __launch_bounds__(SEL_T) void select_kernel(const float* __restrict__ x,
                                                       const float* __restrict__ curv,
                                                       const int* __restrict__ idxs,
                                                       float* __restrict__ out) {
  const int b = blockIdx.x;
  const int t = threadIdx.x;
  __shared__ u64 ka[SS];     // sca keys: (~vbits, i)  -> ascending == desc by v
  __shared__ u64 kb[4096];   // scb keys: (vbits, i)   -> ascending, 1024 pads
  __shared__ float rmn[8], rmx[8];

  const float* cb = curv + (size_t)b * NN;
  const int* ib = idxs + (size_t)b * NN;

  float mn = __builtin_inff(), mx = -__builtin_inff();
  float cv[8];
#pragma unroll
  for (int q = 0; q < 8; ++q) {
    float v = cb[q * SEL_T + t];
    cv[q] = v;
    mn = fminf(mn, v);
    mx = fmaxf(mx, v);
  }
#pragma unroll
  for (int s = 1; s < 64; s <<= 1) {
    mn = fminf(mn, __shfl_xor(mn, s, 64));
    mx = fmaxf(mx, __shfl_xor(mx, s, 64));
  }
  if ((t & 63) == 0) { rmn[t >> 6] = mn; rmx[t >> 6] = mx; }
  __syncthreads();
  mn = rmn[0]; mx = rmx[0];
#pragma unroll
  for (int w = 1; w < 8; ++w) { mn = fminf(mn, rmn[w]); mx = fmaxf(mx, rmx[w]); }
  float denom = __fsub_rn(mx, mn);

#pragma unroll
  for (int q = 0; q < 8; ++q) {
    int i = q * SEL_T + t;
    float cn = __fdiv_rn(__fsub_rn(cv[q], mn), denom);
    int id = ib[i];
    // jnp.linspace(1,0,4096)[id] = 1 - id/4095 (true division; id=4095 -> 0)
    float sv = __fsub_rn(1.0f, __fdiv_rn((float)id, 4095.0f));
    float scv = __fmul_rn(sv, cn);   // sc >= 0 -> bits are order-monotone
    u32 vb = __float_as_uint(scv);
    if (i < SS)
      ka[i] = ((u64)(vb ^ 0xFFFFFFFFu) << 32) | (u32)i;
    else
      kb[i - SS] = ((u64)vb << 32) | (u32)(i - SS);
  }
  for (int i = NBB + t; i < 4096; i += SEL_T) kb[i] = ~0ULL;  // pads to the top
  __syncthreads();

  // bitonic sort ka ascending (n=1024, 512 pairs: one per thread)
  for (u32 k = 2; k <= SS; k <<= 1) {
    for (u32 j = k >> 1; j > 0; j >>= 1) {
      u32 p = (u32)t;
      u32 i = ((p & ~(j - 1)) << 1) | (p & (j - 1));
      u32 l = i | j;
      bool up = ((i & k) == 0);
      u64 a = ka[i], c = ka[l];
      if ((a > c) == up) { ka[i] = c; ka[l] = a; }
      __syncthreads();
    }
  }
  // bitonic sort kb ascending (n=4096, 2048 pairs: 4 per thread)
  for (u32 k = 2; k <= 4096; k <<= 1) {
    for (u32 j = k >> 1; j > 0; j >>= 1) {
#pragma unroll
      for (u32 p = (u32)t; p < 2048; p += SEL_T) {
        u32 i = ((p & ~(j - 1)) << 1) | (p & (j - 1));
        u32 l = i | j;
        bool up = ((i & k) == 0);
        u64 a = kb[i], c = kb[l];
        if ((a > c) == up) { kb[i] = c; kb[l] = a; }
      }
      __syncthreads();
    }
  }

  // final[j]: j<922 -> ba_idx[j]; else tb beats ba ? tb_idx[j] : ba_idx[j]
#pragma unroll
  for (int j0 = 0; j0 < SS; j0 += SEL_T) {
    int j = j0 + t;
    u64 A = ka[j];
    int baid = (int)(u32)(A & 0xFFFFFFFFu);
    u32 babits = ((u32)(A >> 32)) ^ 0xFFFFFFFFu;
    int fin = baid;
    if (j >= SS - EE) {
      u64 Bk = kb[2048 + j];           // largest-1024 of scb, ascending
      u32 tbbits = (u32)(Bk >> 32);
      if (tbbits > babits) fin = (int)(u32)(Bk & 0xFFFFFFFFu) + SS;
    }
    int pt = ib[fin];
    out[(size_t)b * SS + j] = (float)fin;
    const float* xp = x + ((size_t)b * NN + (size_t)pt) * 3;
    float* op = out + (size_t)BB * SS + ((size_t)b * SS + (size_t)j) * 3;
    op[0] = xp[0];
    op[1] = xp[1];
    op[2] = xp[2];
  }
}

extern "C" void kernel_launch(void* const* d_in, const int* in_sizes, int n_in,
                              void* d_out, int out_size, void* d_ws, size_t ws_size,
                              hipStream_t stream) {
  (void)in_sizes; (void)n_in; (void)out_size; (void)ws_size;
  const float* x = (const float*)d_in[0];
  const float* curv = (const float*)d_in[1];
  int* idxs = (int*)d_ws;             // B*N int32 = 128 KB scratch
  float* out = (float*)d_out;

  fps_kernel<<<BB, FT, 0, stream>>>(x, idxs);
  select_kernel<<<BB, SEL_T, 0, stream>>>(x, curv, idxs, out);
}

// Round 11
// 2504.772 us; speedup vs baseline: 1.0283x; 1.0283x over previous
//
#include <hip/hip_runtime.h>
#include <stdint.h>

// Forbid mul+add contraction: pk_fma would change rounding vs the reference's
// separate mul/add ops. Critical scalar math also uses explicit __f*_rn.
#pragma clang fp contract(off)

typedef unsigned long long u64;
typedef unsigned int u32;
typedef float v2f __attribute__((ext_vector_type(2)));

#define BB 8
#define NN 4096
#define SS 1024
#define EE 102      // int(0.1 * 1024)
#define NBB 3072    // N - S
#define FT 512      // fps threads (8 waves, 2 per SIMD -> TLP latency hiding)
#define PT 8        // points per thread (contiguous: thread t owns [8t,8t+8))
#define NW 8        // waves
#define SEL_T 512

// DPP wave64 max-reduce step (bound_ctrl: OOB lanes read 0; values >= 0).
template <int CTRL>
__device__ __forceinline__ float maxdpp(float v) {
  int m = __builtin_amdgcn_update_dpp(0, __float_as_int(v), CTRL, 0xf, 0xf, true);
  return fmaxf(v, __int_as_float(m));
}

// ---------------- FPS kernel: one block per batch ----------------
// Exact replica of _fps_order: d = (dx*dx+dy*dy)+dz*dz (no FMA), mind=min,
// argmax with lowest-index-first ties. r6 proven structure, re-parameterized
// to 8 waves x 8 pts/lane: halves the serial per-lane select chain and lets
// two waves per SIMD fill each other's dep stalls. Scalar register arrays +
// 64KB AoS mirror (demotion shield + broadcast source; rounds 5/7/8 lesson).
// idxs go to LDS hist[] (lgkm ack only), flushed coalesced after the loop.
__global__ __launch_bounds__(FT) void fps_kernel(const float* __restrict__ x,
                                                 int* __restrict__ idxs) {
  const int b = blockIdx.x;
  const int t = threadIdx.x;
  const int w = t >> 6;
  const int lane = t & 63;
  const float* xb = x + (size_t)b * NN * 3;

  __shared__ float4 lxyz[NN];   // 64 KB coord mirror (+ demotion shield)
  __shared__ int hist[NN];      // 16 KB FPS order (LDS-local until flush)
  __shared__ u64 rkey[2][NW];   // per-wave candidate keys, double-buffered

  float px[PT], py[PT], pz[PT], mind[PT];

  // load 8 contiguous points = 6 float4 per thread (fully coalesced block)
  const float4* xb4 = (const float4*)xb;
  float4 f[6];
#pragma unroll
  for (int j = 0; j < 6; ++j) f[j] = xb4[t * 6 + j];
#pragma unroll
  for (int g = 0; g < 2; ++g) {
    float4 a = f[g * 3 + 0], c = f[g * 3 + 1], d = f[g * 3 + 2];
    px[g * 4 + 0] = a.x; py[g * 4 + 0] = a.y; pz[g * 4 + 0] = a.z;
    px[g * 4 + 1] = a.w; py[g * 4 + 1] = c.x; pz[g * 4 + 1] = c.y;
    px[g * 4 + 2] = c.z; py[g * 4 + 2] = c.w; pz[g * 4 + 2] = d.x;
    px[g * 4 + 3] = d.y; py[g * 4 + 3] = d.z; pz[g * 4 + 3] = d.w;
  }
#pragma unroll
  for (int q = 0; q < PT; ++q) {
    lxyz[t * PT + q] = make_float4(px[q], py[q], pz[q], 0.0f);
    mind[q] = __builtin_inff();
  }
  if (t == 0) hist[0] = 0;
  __syncthreads();

  float4 lp = lxyz[0];
  for (int it = 0; it < NN - 1; ++it) {
    const int buf = it & 1;
    v2f lx2; lx2.x = lp.x; lx2.y = lp.x;
    v2f ly2; ly2.x = lp.y; ly2.y = lp.y;
    v2f lz2; lz2.x = lp.z; lz2.y = lp.z;

    // phase 1: packed-f32 distances + mind update + serial lowest-index
    // select (8-deep now; per-half rn rounding == scalar rn)
    float bestv = -1.0f;
    int bq = 0;
#pragma unroll
    for (int q = 0; q < 4; ++q) {
      v2f X; X.x = px[2 * q]; X.y = px[2 * q + 1];
      v2f Y; Y.x = py[2 * q]; Y.y = py[2 * q + 1];
      v2f Z; Z.x = pz[2 * q]; Z.y = pz[2 * q + 1];
      v2f dx = X - lx2;
      v2f dy = Y - ly2;
      v2f dz = Z - lz2;
      v2f dd = (dx * dx + dy * dy) + dz * dz;
      float m0 = fminf(mind[2 * q], dd.x);
      float m1 = fminf(mind[2 * q + 1], dd.y);
      mind[2 * q] = m0;
      mind[2 * q + 1] = m1;
      // ascending q => ascending global index; strict '>' keeps lowest index
      if (m0 > bestv) { bestv = m0; bq = 2 * q; }
      if (m1 > bestv) { bestv = m1; bq = 2 * q + 1; }
    }
    int besti = t * PT + bq;

    // phase 2: wave64 max via DPP (all VALU), result in lane 63
    float r = bestv;
    r = maxdpp<0x111>(r);   // row_shr:1
    r = maxdpp<0x112>(r);   // row_shr:2
    r = maxdpp<0x114>(r);   // row_shr:4
    r = maxdpp<0x118>(r);   // row_shr:8
    r = maxdpp<0x142>(r);   // row_bcast:15
    r = maxdpp<0x143>(r);   // row_bcast:31
    int wmaxb = __builtin_amdgcn_readlane(__float_as_int(r), 63);

    // phase 3: lowest lane holding the max == lowest candidate index
    u64 msk = __ballot(__float_as_int(bestv) == wmaxb);
    int flane = __ffsll((long long)msk) - 1;
    int widx = __builtin_amdgcn_readlane(besti, flane);

    u64 key = ((u64)(u32)wmaxb << 32) | (u32)(0xFFFFFFFFu - (u32)widx);
    if (lane == 0) rkey[buf][w] = key;
    __syncthreads();

    // phase 4: 8-way key tree (value desc, index asc packed in u64);
    // slot reads are wave-uniform -> LDS broadcast, no conflicts
    u64 k0 = rkey[buf][0], k1 = rkey[buf][1];
    u64 k2 = rkey[buf][2], k3 = rkey[buf][3];
    u64 k4 = rkey[buf][4], k5 = rkey[buf][5];
    u64 k6 = rkey[buf][6], k7 = rkey[buf][7];
    u64 m01 = k0 > k1 ? k0 : k1;
    u64 m23 = k2 > k3 ? k2 : k3;
    u64 m45 = k4 > k5 ? k4 : k5;
    u64 m67 = k6 > k7 ? k6 : k7;
    u64 m03 = m01 > m23 ? m01 : m23;
    u64 m47 = m45 > m67 ? m45 : m67;
    u64 km = m03 > m47 ? m03 : m47;
    int last = (int)(0xFFFFFFFFu - (u32)(km & 0xFFFFFFFFu));
    if (t == 0) hist[it + 1] = last;   // LDS store: lgkm ack only, no vmcnt
    lp = lxyz[last];                   // broadcast read (same addr all lanes)
  }

  // flush FPS order to global once (coalesced int4: 4096/512/4 = 2 per thread)
  __syncthreads();
  int* ig = idxs + (size_t)b * NN;
#pragma unroll
  for (int j = 0; j < NN / FT / 4; ++j) {
    ((int4*)ig)[j * FT + t] = ((const int4*)hist)[j * FT + t];
  }
}

// ------------- selection kernel: one block per batch -------------
__global__ __launch_bounds__(SEL_T) void select_kernel(const float* __restrict__ x,
                                                       const float* __restrict__ curv,
                                                       const int* __restrict__ idxs,
                                                       float* __restrict__ out) {
  const int b = blockIdx.x;
  const int t = threadIdx.x;
  __shared__ u64 ka[SS];     // sca keys: (~vbits, i)  -> ascending == desc by v
  __shared__ u64 kb[4096];   // scb keys: (vbits, i)   -> ascending, 1024 pads
  __shared__ float rmn[8], rmx[8];

  const float* cb = curv + (size_t)b * NN;
  const int* ib = idxs + (size_t)b * NN;

  float mn = __builtin_inff(), mx = -__builtin_inff();
  float cv[8];
#pragma unroll
  for (int q = 0; q < 8; ++q) {
    float v = cb[q * SEL_T + t];
    cv[q] = v;
    mn = fminf(mn, v);
    mx = fmaxf(mx, v);
  }
#pragma unroll
  for (int s = 1; s < 64; s <<= 1) {
    mn = fminf(mn, __shfl_xor(mn, s, 64));
    mx = fmaxf(mx, __shfl_xor(mx, s, 64));
  }
  if ((t & 63) == 0) { rmn[t >> 6] = mn; rmx[t >> 6] = mx; }
  __syncthreads();
  mn = rmn[0]; mx = rmx[0];
#pragma unroll
  for (int w = 1; w < 8; ++w) { mn = fminf(mn, rmn[w]); mx = fmaxf(mx, rmx[w]); }
  float denom = __fsub_rn(mx, mn);

#pragma unroll
  for (int q = 0; q < 8; ++q) {
    int i = q * SEL_T + t;
    float cn = __fdiv_rn(__fsub_rn(cv[q], mn), denom);
    int id = ib[i];
    // jnp.linspace(1,0,4096)[id] = 1 - id/4095 (true division; id=4095 -> 0)
    float sv = __fsub_rn(1.0f, __fdiv_rn((float)id, 4095.0f));
    float scv = __fmul_rn(sv, cn);   // sc >= 0 -> bits are order-monotone
    u32 vb = __float_as_uint(scv);
    if (i < SS)
      ka[i] = ((u64)(vb ^ 0xFFFFFFFFu) << 32) | (u32)i;
    else
      kb[i - SS] = ((u64)vb << 32) | (u32)(i - SS);
  }
  for (int i = NBB + t; i < 4096; i += SEL_T) kb[i] = ~0ULL;  // pads to the top
  __syncthreads();

  // bitonic sort ka ascending (n=1024, 512 pairs: one per thread)
  for (u32 k = 2; k <= SS; k <<= 1) {
    for (u32 j = k >> 1; j > 0; j >>= 1) {
      u32 p = (u32)t;
      u32 i = ((p & ~(j - 1)) << 1) | (p & (j - 1));
      u32 l = i | j;
      bool up = ((i & k) == 0);
      u64 a = ka[i], c = ka[l];
      if ((a > c) == up) { ka[i] = c; ka[l] = a; }
      __syncthreads();
    }
  }
  // bitonic sort kb ascending (n=4096, 2048 pairs: 4 per thread)
  for (u32 k = 2; k <= 4096; k <<= 1) {
    for (u32 j = k >> 1; j > 0; j >>= 1) {
#pragma unroll
      for (u32 p = (u32)t; p < 2048; p += SEL_T) {
        u32 i = ((p & ~(j - 1)) << 1) | (p & (j - 1));
        u32 l = i | j;
        bool up = ((i & k) == 0);
        u64 a = kb[i], c = kb[l];
        if ((a > c) == up) { kb[i] = c; kb[l] = a; }
      }
      __syncthreads();
    }
  }

  // final[j]: j<922 -> ba_idx[j]; else tb beats ba ? tb_idx[j] : ba_idx[j]
#pragma unroll
  for (int j0 = 0; j0 < SS; j0 += SEL_T) {
    int j = j0 + t;
    u64 A = ka[j];
    int baid = (int)(u32)(A & 0xFFFFFFFFu);
    u32 babits = ((u32)(A >> 32)) ^ 0xFFFFFFFFu;
    int fin = baid;
    if (j >= SS - EE) {
      u64 Bk = kb[2048 + j];           // largest-1024 of scb, ascending
      u32 tbbits = (u32)(Bk >> 32);
      if (tbbits > babits) fin = (int)(u32)(Bk & 0xFFFFFFFFu) + SS;
    }
    int pt = ib[fin];
    out[(size_t)b * SS + j] = (float)fin;
    const float* xp = x + ((size_t)b * NN + (size_t)pt) * 3;
    float* op = out + (size_t)BB * SS + ((size_t)b * SS + (size_t)j) * 3;
    op[0] = xp[0];
    op[1] = xp[1];
    op[2] = xp[2];
  }
}

extern "C" void kernel_launch(void* const* d_in, const int* in_sizes, int n_in,
                              void* d_out, int out_size, void* d_ws, size_t ws_size,
                              hipStream_t stream) {
  (void)in_sizes; (void)n_in; (void)out_size; (void)ws_size;
  const float* x = (const float*)d_in[0];
  const float* curv = (const float*)d_in[1];
  int* idxs = (int*)d_ws;             // B*N int32 = 128 KB scratch
  float* out = (float*)d_out;

  fps_kernel<<<BB, FT, 0, stream>>>(x, idxs);
  select_kernel<<<BB, SEL_T, 0, stream>>>(x, curv, idxs, out);
}

// Round 12
// 2242.841 us; speedup vs baseline: 1.1484x; 1.1168x over previous
//
#include <hip/hip_runtime.h>
#include <stdint.h>

// Forbid mul+add contraction: pk_fma would change rounding vs the reference's
// separate mul/add ops. Critical scalar math also uses explicit __f*_rn.
#pragma clang fp contract(off)

typedef unsigned long long u64;
typedef unsigned int u32;
typedef float v2f __attribute__((ext_vector_type(2)));

#define BB 8
#define NN 4096
#define SS 1024
#define EE 102      // int(0.1 * 1024)
#define NBB 3072    // N - S
#define FT 256      // fps threads (4 waves, 1 per SIMD)
#define PT 16       // points per thread (contiguous: thread t owns [16t,16t+16))
#define SEL_T 512

// DPP wave64 max-reduce step (bound_ctrl: OOB lanes read 0; values >= 0).
template <int CTRL>
__device__ __forceinline__ float maxdpp(float v) {
  int m = __builtin_amdgcn_update_dpp(0, __float_as_int(v), CTRL, 0xf, 0xf, true);
  return fmaxf(v, __int_as_float(m));
}

// ---------------- FPS kernel: one block per batch ----------------
// Exact replica of _fps_order: d = (dx*dx+dy*dy)+dz*dz (no FMA), mind=min,
// argmax with lowest-index-first ties. r6 proven base (scalar register
// arrays + 64KB AoS mirror: broadcast source AND PromoteAlloca demotion
// shield -- rounds 5/7/8). Two tail-only edits vs r6:
//  (a) per-iter winner index goes to LDS hist[] (lgkm-only ack), flushed
//      coalesced after the loop -- no global write-ack in the per-iter
//      pre-barrier vmcnt(0) drain;
//  (b) the winning lane writes the key itself (it owns besti) -- removes
//      the serial second readlane.
__global__ __launch_bounds__(FT) void fps_kernel(const float* __restrict__ x,
                                                 int* __restrict__ idxs) {
  const int b = blockIdx.x;
  const int t = threadIdx.x;
  const int w = t >> 6;
  const int lane = t & 63;
  const float* xb = x + (size_t)b * NN * 3;

  __shared__ float4 lxyz[NN];   // 64 KB coord mirror (+ demotion shield)
  __shared__ int hist[NN];      // 16 KB FPS order (LDS-local until flush)
  __shared__ u64 rkey[2][4];    // per-wave candidate keys, double-buffered

  float px[PT], py[PT], pz[PT], mind[PT];

  // load 16 contiguous points = 12 float4 per thread (fully coalesced block)
  const float4* xb4 = (const float4*)xb;
  float4 f[12];
#pragma unroll
  for (int j = 0; j < 12; ++j) f[j] = xb4[t * 12 + j];
#pragma unroll
  for (int g = 0; g < 4; ++g) {
    float4 a = f[g * 3 + 0], c = f[g * 3 + 1], d = f[g * 3 + 2];
    px[g * 4 + 0] = a.x; py[g * 4 + 0] = a.y; pz[g * 4 + 0] = a.z;
    px[g * 4 + 1] = a.w; py[g * 4 + 1] = c.x; pz[g * 4 + 1] = c.y;
    px[g * 4 + 2] = c.z; py[g * 4 + 2] = c.w; pz[g * 4 + 2] = d.x;
    px[g * 4 + 3] = d.y; py[g * 4 + 3] = d.z; pz[g * 4 + 3] = d.w;
  }
#pragma unroll
  for (int q = 0; q < PT; ++q) {
    lxyz[t * PT + q] = make_float4(px[q], py[q], pz[q], 0.0f);
    mind[q] = __builtin_inff();
  }
  if (t == 0) hist[0] = 0;
  __syncthreads();

  float4 lp = lxyz[0];
  for (int it = 0; it < NN - 1; ++it) {
    const int buf = it & 1;
    v2f lx2; lx2.x = lp.x; lx2.y = lp.x;
    v2f ly2; ly2.x = lp.y; ly2.y = lp.y;
    v2f lz2; lz2.x = lp.z; lz2.y = lp.z;

    // phase 1: packed-f32 distances + mind update + serial lowest-index
    // select (r6 proven; per-half rn rounding == scalar rn)
    float bestv = -1.0f;
    int bq = 0;
#pragma unroll
    for (int q = 0; q < 8; ++q) {
      v2f X; X.x = px[2 * q]; X.y = px[2 * q + 1];
      v2f Y; Y.x = py[2 * q]; Y.y = py[2 * q + 1];
      v2f Z; Z.x = pz[2 * q]; Z.y = pz[2 * q + 1];
      v2f dx = X - lx2;
      v2f dy = Y - ly2;
      v2f dz = Z - lz2;
      v2f dd = (dx * dx + dy * dy) + dz * dz;
      float m0 = fminf(mind[2 * q], dd.x);
      float m1 = fminf(mind[2 * q + 1], dd.y);
      mind[2 * q] = m0;
      mind[2 * q + 1] = m1;
      // ascending q => ascending global index; strict '>' keeps lowest index
      if (m0 > bestv) { bestv = m0; bq = 2 * q; }
      if (m1 > bestv) { bestv = m1; bq = 2 * q + 1; }
    }

    // phase 2: wave64 max via DPP (all VALU): result in lane 63
    float r = bestv;
    r = maxdpp<0x111>(r);   // row_shr:1
    r = maxdpp<0x112>(r);   // row_shr:2
    r = maxdpp<0x114>(r);   // row_shr:4
    r = maxdpp<0x118>(r);   // row_shr:8
    r = maxdpp<0x142>(r);   // row_bcast:15
    r = maxdpp<0x143>(r);   // row_bcast:31
    int wmaxb = __builtin_amdgcn_readlane(__float_as_int(r), 63);

    // phase 3: first lane holding the max == lowest candidate index; that
    // lane publishes the key itself (no second readlane)
    u64 msk = __ballot(__float_as_int(bestv) == wmaxb);
    int flane = (int)__builtin_ctzll(msk);
    if (lane == flane) {
      int besti = t * PT + bq;
      rkey[buf][w] = ((u64)(u32)wmaxb << 32) | (u32)(0xFFFFFFFFu - (u32)besti);
    }
    __syncthreads();

    // phase 4: 4-way key tree (value desc, index asc packed in u64);
    // slot reads are wave-uniform -> LDS broadcast
    u64 k0 = rkey[buf][0], k1 = rkey[buf][1];
    u64 k2 = rkey[buf][2], k3 = rkey[buf][3];
    u64 m01 = k0 > k1 ? k0 : k1;
    u64 m23 = k2 > k3 ? k2 : k3;
    u64 km = m01 > m23 ? m01 : m23;
    int last = (int)(0xFFFFFFFFu - (u32)(km & 0xFFFFFFFFu));
    if (t == 0) hist[it + 1] = last;   // LDS store: lgkm ack only, no vmcnt
    lp = lxyz[last];                   // broadcast read (same addr all lanes)
  }

  // flush FPS order to global once (coalesced int4: 4096/256/4 = 4 per thread)
  __syncthreads();
  int* ig = idxs + (size_t)b * NN;
#pragma unroll
  for (int j = 0; j < NN / FT / 4; ++j) {
    ((int4*)ig)[j * FT + t] = ((const int4*)hist)[j * FT + t];
  }
}

// ------------- selection kernel: one block per batch -------------
__global__ __launch_bounds__(SEL_T) void select_kernel(const float* __restrict__ x,
                                                       const float* __restrict__ curv,
                                                       const int* __restrict__ idxs,
                                                       float* __restrict__ out) {
  const int b = blockIdx.x;
  const int t = threadIdx.x;
  __shared__ u64 ka[SS];     // sca keys: (~vbits, i)  -> ascending == desc by v
  __shared__ u64 kb[4096];   // scb keys: (vbits, i)   -> ascending, 1024 pads
  __shared__ float rmn[8], rmx[8];

  const float* cb = curv + (size_t)b * NN;
  const int* ib = idxs + (size_t)b * NN;

  float mn = __builtin_inff(), mx = -__builtin_inff();
  float cv[8];
#pragma unroll
  for (int q = 0; q < 8; ++q) {
    float v = cb[q * SEL_T + t];
    cv[q] = v;
    mn = fminf(mn, v);
    mx = fmaxf(mx, v);
  }
#pragma unroll
  for (int s = 1; s < 64; s <<= 1) {
    mn = fminf(mn, __shfl_xor(mn, s, 64));
    mx = fmaxf(mx, __shfl_xor(mx, s, 64));
  }
  if ((t & 63) == 0) { rmn[t >> 6] = mn; rmx[t >> 6] = mx; }
  __syncthreads();
  mn = rmn[0]; mx = rmx[0];
#pragma unroll
  for (int w = 1; w < 8; ++w) { mn = fminf(mn, rmn[w]); mx = fmaxf(mx, rmx[w]); }
  float denom = __fsub_rn(mx, mn);

#pragma unroll
  for (int q = 0; q < 8; ++q) {
    int i = q * SEL_T + t;
    float cn = __fdiv_rn(__fsub_rn(cv[q], mn), denom);
    int id = ib[i];
    // jnp.linspace(1,0,4096)[id] = 1 - id/4095 (true division; id=4095 -> 0)
    float sv = __fsub_rn(1.0f, __fdiv_rn((float)id, 4095.0f));
    float scv = __fmul_rn(sv, cn);   // sc >= 0 -> bits are order-monotone
    u32 vb = __float_as_uint(scv);
    if (i < SS)
      ka[i] = ((u64)(vb ^ 0xFFFFFFFFu) << 32) | (u32)i;
    else
      kb[i - SS] = ((u64)vb << 32) | (u32)(i - SS);
  }
  for (int i = NBB + t; i < 4096; i += SEL_T) kb[i] = ~0ULL;  // pads to the top
  __syncthreads();

  // bitonic sort ka ascending (n=1024, 512 pairs: one per thread)
  for (u32 k = 2; k <= SS; k <<= 1) {
    for (u32 j = k >> 1; j > 0; j >>= 1) {
      u32 p = (u32)t;
      u32 i = ((p & ~(j - 1)) << 1) | (p & (j - 1));
      u32 l = i | j;
      bool up = ((i & k) == 0);
      u64 a = ka[i], c = ka[l];
      if ((a > c) == up) { ka[i] = c; ka[l] = a; }
      __syncthreads();
    }
  }
  // bitonic sort kb ascending (n=4096, 2048 pairs: 4 per thread)
  for (u32 k = 2; k <= 4096; k <<= 1) {
    for (u32 j = k >> 1; j > 0; j >>= 1) {
#pragma unroll
      for (u32 p = (u32)t; p < 2048; p += SEL_T) {
        u32 i = ((p & ~(j - 1)) << 1) | (p & (j - 1));
        u32 l = i | j;
        bool up = ((i & k) == 0);
        u64 a = kb[i], c = kb[l];
        if ((a > c) == up) { kb[i] = c; kb[l] = a; }
      }
      __syncthreads();
    }
  }

  // final[j]: j<922 -> ba_idx[j]; else tb beats ba ? tb_idx[j] : ba_idx[j]
#pragma unroll
  for (int j0 = 0; j0 < SS; j0 += SEL_T) {
    int j = j0 + t;
    u64 A = ka[j];
    int baid = (int)(u32)(A & 0xFFFFFFFFu);
    u32 babits = ((u32)(A >> 32)) ^ 0xFFFFFFFFu;
    int fin = baid;
    if (j >= SS - EE) {
      u64 Bk = kb[2048 + j];           // largest-1024 of scb, ascending
      u32 tbbits = (u32)(Bk >> 32);
      if (tbbits > babits) fin = (int)(u32)(Bk & 0xFFFFFFFFu) + SS;
    }
    int pt = ib[fin];
    out[(size_t)b * SS + j] = (float)fin;
    const float* xp = x + ((size_t)b * NN + (size_t)pt) * 3;
    float* op = out + (size_t)BB * SS + ((size_t)b * SS + (size_t)j) * 3;
    op[0] = xp[0];
    op[1] = xp[1];
    op[2] = xp[2];
  }
}

extern "C" void kernel_launch(void* const* d_in, const int* in_sizes, int n_in,
                              void* d_out, int out_size, void* d_ws, size_t ws_size,
                              hipStream_t stream) {
  (void)in_sizes; (void)n_in; (void)out_size; (void)ws_size;
  const float* x = (const float*)d_in[0];
  const float* curv = (const float*)d_in[1];
  int* idxs = (int*)d_ws;             // B*N int32 = 128 KB scratch
  float* out = (float*)d_out;

  fps_kernel<<<BB, FT, 0, stream>>>(x, idxs);
  select_kernel<<<BB, SEL_T, 0, stream>>>(x, curv, idxs, out);
}